// Round 14
// baseline (133.423 us; speedup 1.0000x reference)
//
#include <hip/hip_runtime.h>
#include <hip/hip_bf16.h>

typedef __attribute__((ext_vector_type(4))) int i32x4;

#define K_DIM 1024
#define I_DIM 4096
#define BK3 64
#define NT3 16  // K_DIM / BK3
// block tile 256(M) x 128(N); 4 waves (2x2), per-wave 128x64, i8 MFMA 16x16x64
// Triple-buffered LDS (72KB, 2 blocks/CU), counted vmcnt(6), 2-tile lead,
// supertile L2 order (r13), SWAPPED mfma operands -> vectorized float4 epilogue.

__device__ __forceinline__ float fakeq_int(float x, float s, float zp) {
    float q = fminf(fmaxf(rintf(x / s) + zp, 0.0f), 255.0f);
    return q - zp;
}

__device__ __forceinline__ float gelu_tanh(float y) {
    float y2 = y * y;
    float z = y * fmaf(0.0356774081f, y2, 0.7978845608f);
    return y / (1.0f + __expf(-2.0f * z));
}

__global__ void quant_x_kernel(const float* __restrict__ x, signed char* __restrict__ Aq,
                               const float* __restrict__ a_scale, const float* __restrict__ a_zero,
                               long long n) {
    long long i = ((long long)blockIdx.x * blockDim.x + threadIdx.x) * 8;
    if (i >= n) return;
    float s = a_scale[0];
    float zp = rintf(a_zero[0]);
    float4 v0 = *(const float4*)(x + i);
    float4 v1 = *(const float4*)(x + i + 4);
    int q0 = (int)fakeq_int(v0.x, s, zp), q1 = (int)fakeq_int(v0.y, s, zp);
    int q2 = (int)fakeq_int(v0.z, s, zp), q3 = (int)fakeq_int(v0.w, s, zp);
    int q4 = (int)fakeq_int(v1.x, s, zp), q5 = (int)fakeq_int(v1.y, s, zp);
    int q6 = (int)fakeq_int(v1.z, s, zp), q7 = (int)fakeq_int(v1.w, s, zp);
    int lo = (q0 & 255) | ((q1 & 255) << 8) | ((q2 & 255) << 16) | ((q3 & 255) << 24);
    int hi = (q4 & 255) | ((q5 & 255) << 8) | ((q6 & 255) << 16) | ((q7 & 255) << 24);
    *(int2*)(Aq + i) = make_int2(lo, hi);
}

__global__ void quant_w_kernel(const float* __restrict__ w, signed char* __restrict__ Wq,
                               const float* __restrict__ w_scale, const float* __restrict__ w_zero,
                               long long n) {
    long long i = ((long long)blockIdx.x * blockDim.x + threadIdx.x) * 8;
    if (i >= n) return;
    long long row = i >> 10;
    float s = w_scale[row];
    float zp = rintf(w_zero[row]);
    float4 v0 = *(const float4*)(w + i);
    float4 v1 = *(const float4*)(w + i + 4);
    int q0 = (int)fakeq_int(v0.x, s, zp), q1 = (int)fakeq_int(v0.y, s, zp);
    int q2 = (int)fakeq_int(v0.z, s, zp), q3 = (int)fakeq_int(v0.w, s, zp);
    int q4 = (int)fakeq_int(v1.x, s, zp), q5 = (int)fakeq_int(v1.y, s, zp);
    int q6 = (int)fakeq_int(v1.z, s, zp), q7 = (int)fakeq_int(v1.w, s, zp);
    int lo = (q0 & 255) | ((q1 & 255) << 8) | ((q2 & 255) << 16) | ((q3 & 255) << 24);
    int hi = (q4 & 255) | ((q5 & 255) << 8) | ((q6 & 255) << 16) | ((q7 & 255) << 24);
    *(int2*)(Wq + i) = make_int2(lo, hi);
}

#define GLL(SRC, DST)                                                         \
    __builtin_amdgcn_global_load_lds(                                         \
        (const __attribute__((address_space(1))) void*)(SRC),                 \
        (__attribute__((address_space(3))) void*)(DST), 16, 0, 0)

// stage K-tile TT (A 256x64B = 4 chunks, B 128x64B = 2 chunks) into buffer BUF
#define STAGE(TT, BUF)                                            \
    do {                                                          \
        GLL(pA0 + (TT) * BK3, As + (BUF) * 16384 + dA);           \
        GLL(pA1 + (TT) * BK3, As + (BUF) * 16384 + 4096 + dA);    \
        GLL(pA2 + (TT) * BK3, As + (BUF) * 16384 + 8192 + dA);    \
        GLL(pA3 + (TT) * BK3, As + (BUF) * 16384 + 12288 + dA);   \
        GLL(pB0 + (TT) * BK3, Bs + (BUF) * 8192 + dA);            \
        GLL(pB1 + (TT) * BK3, Bs + (BUF) * 8192 + 4096 + dA);     \
    } while (0)

__global__ __launch_bounds__(256, 2) void gemm_gelu_kernel(
    const signed char* __restrict__ Aq,   // [M][K] int8 codes
    const signed char* __restrict__ Wq,   // [I][K]
    const float* __restrict__ bias,
    const float* __restrict__ w_scale,
    const float* __restrict__ a_scale,
    float* __restrict__ out,              // [M][I] fp32
    int M, int Mtiles, int Ntiles) {
    __shared__ alignas(16) signed char As[3 * 256 * BK3];  // 48 KB
    __shared__ alignas(16) signed char Bs[3 * 128 * BK3];  // 24 KB

    // bijective XCD-aware swizzle (nwg % 8 == 0)
    int nwg = gridDim.x, bid = blockIdx.x;
    int xcd = bid & 7, lin = bid >> 3;
    int q8 = nwg >> 3, r8 = nwg & 7;
    int swz = (xcd < r8 ? xcd * (q8 + 1) : r8 * (q8 + 1) + (xcd - r8) * q8) + lin;

    // supertile order (r13): bands of 4 mt, nt-major, mt inner
    int band = swz >> 7;                 // / (4 * Ntiles), Ntiles == 32
    int r = swz & 127;
    int rem = Mtiles - band * 4;
    if (rem > 4) rem = 4;
    unsigned nt = (unsigned)r / (unsigned)rem;
    int mt = band * 4 + (r - (int)nt * rem);

    int tid = threadIdx.x;
    int wave = tid >> 6, lane = tid & 63;
    int wr = wave >> 1, wc = wave & 1;  // 2x2 waves, per-wave 128(M) x 64(N)

    long long mrow0 = (long long)mt * 256;
    int ncol0 = (int)nt * 128;

    // staging: thread t covers row (chunk*64 + t>>2), LDS slot j = t&3 (16B slots).
    // rotation swizzle (HW-verified r6: 0 conflicts): LDS[row][j] = src slot (j-(row>>1))&3
    int r0 = tid >> 2;
    int slotsrc = ((tid & 3) - ((tid >> 3) & 3)) & 3;
    long long mmax = (long long)M - 1;
    long long raA0 = mrow0 + r0;         if (raA0 > mmax) raA0 = mmax;
    long long raA1 = mrow0 + 64 + r0;    if (raA1 > mmax) raA1 = mmax;
    long long raA2 = mrow0 + 128 + r0;   if (raA2 > mmax) raA2 = mmax;
    long long raA3 = mrow0 + 192 + r0;   if (raA3 > mmax) raA3 = mmax;
    const signed char* pA0 = Aq + raA0 * K_DIM + slotsrc * 16;
    const signed char* pA1 = Aq + raA1 * K_DIM + slotsrc * 16;
    const signed char* pA2 = Aq + raA2 * K_DIM + slotsrc * 16;
    const signed char* pA3 = Aq + raA3 * K_DIM + slotsrc * 16;
    const signed char* pB0 = Wq + ((long long)ncol0 + r0) * K_DIM + slotsrc * 16;
    const signed char* pB1 = Wq + ((long long)ncol0 + 64 + r0) * K_DIM + slotsrc * 16;
    int dA = tid * 16;

    // ds_read: lane (r = lane&15, q = lane>>4) reads slot (q + (r>>1)) & 3
    int koffb = (((lane >> 4) + ((lane >> 1) & 3)) & 3) * 16;
    int arowb = wr * 128 + (lane & 15);
    int browb = wc * 64 + (lane & 15);

    i32x4 acc[8][4];
#pragma unroll
    for (int m = 0; m < 8; ++m)
#pragma unroll
        for (int n = 0; n < 4; ++n) acc[m][n] = (i32x4)0;

    // prologue: stage tiles 0,1; wait tile 0 (tile 1's 6 stay in flight)
    STAGE(0, 0);
    STAGE(1, 1);
    asm volatile("s_waitcnt vmcnt(6)" ::: "memory");
    __builtin_amdgcn_s_barrier();

#pragma unroll
    for (int t = 0; t < NT3; ++t) {
        const int buf = t % 3;
        const int bs2 = (t + 2) % 3;
        if (t + 2 < NT3) STAGE(t + 2, bs2);  // 2-tile lead

        i32x4 a[8], b[4];
#pragma unroll
        for (int mi = 0; mi < 8; ++mi)
            a[mi] = *(const i32x4*)(As + buf * 16384 + (arowb + mi * 16) * BK3 + koffb);
#pragma unroll
        for (int n = 0; n < 4; ++n)
            b[n] = *(const i32x4*)(Bs + buf * 8192 + (browb + n * 16) * BK3 + koffb);

        __builtin_amdgcn_s_setprio(1);
        // SWAPPED operands: D = mfma(b, a) -> reg dim indexes B-cols, lane&15 = A-row.
        // acc[mi][n][reg]: row = mrow0+wr*128+mi*16+(lane&15),
        //                  col = ncol0+wc*64+n*16+(lane>>4)*4+reg  (4 consecutive cols/lane)
#pragma unroll
        for (int mi = 0; mi < 8; ++mi)
#pragma unroll
            for (int n = 0; n < 4; ++n)
                acc[mi][n] = __builtin_amdgcn_mfma_i32_16x16x64_i8(b[n], a[mi], acc[mi][n], 0, 0, 0);
        __builtin_amdgcn_s_setprio(0);

        if (t + 2 < NT3) {
            asm volatile("s_waitcnt vmcnt(6)" ::: "memory");
        } else if (t + 1 < NT3) {
            asm volatile("s_waitcnt vmcnt(0)" ::: "memory");
        }
        if (t + 1 < NT3) __builtin_amdgcn_s_barrier();
    }

    // epilogue: vectorized — each lane owns 4 consecutive cols per (mi,n)
    float asc = a_scale[0];
    long long row0 = mrow0 + wr * 128 + (lane & 15);
    int colg0 = ncol0 + wc * 64 + ((lane >> 4) << 2);
    bool fullTile = (mrow0 + 256 <= (long long)M);
#pragma unroll
    for (int n = 0; n < 4; ++n) {
        int colg = colg0 + n * 16;
        float4 sc4 = *(const float4*)(w_scale + colg);
        float4 b4 = *(const float4*)(bias + colg);
        sc4.x *= asc; sc4.y *= asc; sc4.z *= asc; sc4.w *= asc;
#pragma unroll
        for (int mi = 0; mi < 8; ++mi) {
            long long rowi = row0 + mi * 16;
            if (fullTile || rowi < M) {
                float4 o;
                o.x = gelu_tanh((float)acc[mi][n][0] * sc4.x + b4.x);
                o.y = gelu_tanh((float)acc[mi][n][1] * sc4.y + b4.y);
                o.z = gelu_tanh((float)acc[mi][n][2] * sc4.z + b4.z);
                o.w = gelu_tanh((float)acc[mi][n][3] * sc4.w + b4.w);
                *(float4*)(out + rowi * I_DIM + colg) = o;
            }
        }
    }
}

// ---- safety-net fallback (workspace too small): naive on-the-fly
__global__ void fallback_kernel(const float* __restrict__ x, const float* __restrict__ w,
                                const float* __restrict__ bias, const float* __restrict__ w_scale,
                                const float* __restrict__ w_zero, const float* __restrict__ a_scale,
                                const float* __restrict__ a_zero, float* __restrict__ out,
                                long long M) {
    long long gid = (long long)blockIdx.x * blockDim.x + threadIdx.x;
    if (gid >= M * I_DIM) return;
    int i = (int)(gid & (I_DIM - 1));
    long long row = gid >> 12;
    float as = a_scale[0], az = rintf(a_zero[0]);
    float wsc = w_scale[i], wz = rintf(w_zero[i]);
    const float* xr = x + row * K_DIM;
    const float* wrp = w + (long long)i * K_DIM;
    float accf = 0.0f;
    for (int k = 0; k < K_DIM; ++k)
        accf += fakeq_int(xr[k], as, az) * fakeq_int(wrp[k], wsc, wz);
    float y = accf * as * wsc + bias[i];
    out[gid] = 0.5f * y * (1.0f + erff(y * 0.70710678118654752f));
}

extern "C" void kernel_launch(void* const* d_in, const int* in_sizes, int n_in,
                              void* d_out, int out_size, void* d_ws, size_t ws_size,
                              hipStream_t stream) {
    const float* x       = (const float*)d_in[0];
    const float* w       = (const float*)d_in[1];
    const float* bias    = (const float*)d_in[2];
    const float* w_scale = (const float*)d_in[3];
    const float* w_zero  = (const float*)d_in[4];
    const float* a_scale = (const float*)d_in[5];
    const float* a_zero  = (const float*)d_in[6];
    float* out = (float*)d_out;

    long long n_x = in_sizes[0];  // M*K
    long long M = n_x / K_DIM;    // 12608
    size_t needA = ((size_t)n_x + 255) & ~(size_t)255;
    size_t needW = (size_t)I_DIM * K_DIM;

    if (ws_size >= needA + needW) {
        signed char* Aq = (signed char*)d_ws;
        signed char* Wq = (signed char*)((char*)d_ws + needA);

        long long blocksX = (n_x / 8 + 255) / 256;
        quant_x_kernel<<<(int)blocksX, 256, 0, stream>>>(x, Aq, a_scale, a_zero, n_x);

        long long ndw = (long long)I_DIM * K_DIM;
        long long blocksW = (ndw / 8 + 255) / 256;
        quant_w_kernel<<<(int)blocksW, 256, 0, stream>>>(w, Wq, w_scale, w_zero, ndw);

        int Mtiles = (int)((M + 255) / 256);  // 50
        int Ntiles = I_DIM / 128;             // 32
        gemm_gelu_kernel<<<Mtiles * Ntiles, 256, 0, stream>>>(Aq, Wq, bias, w_scale, a_scale,
                                                              out, (int)M, Mtiles, Ntiles);
    } else {
        long long total = M * I_DIM;
        long long blocks = (total + 255) / 256;
        fallback_kernel<<<(int)blocks, 256, 0, stream>>>(x, w, bias, w_scale, w_zero,
                                                         a_scale, a_zero, out, M);
    }
}

// Round 15
// 119.854 us; speedup vs baseline: 1.1132x; 1.1132x over previous
//
#include <hip/hip_runtime.h>
#include <hip/hip_bf16.h>

typedef __attribute__((ext_vector_type(4))) int i32x4;

#define K_DIM 1024
#define I_DIM 4096
#define BK3 64
#define NT3 16  // K_DIM / BK3
// block tile 256(M) x 128(N); 8 waves (4Mx2N), per-wave 64x64, i8 MFMA 16x16x64
// Triple-buffered LDS (72KB, 2 blocks/CU = 16 waves/CU), counted vmcnt(3),
// 2-tile lead, supertile L2 order, rotation swizzle. r13 core at 2x TLP.

__device__ __forceinline__ float fakeq_int(float x, float s, float zp) {
    float q = fminf(fmaxf(rintf(x / s) + zp, 0.0f), 255.0f);
    return q - zp;
}

__device__ __forceinline__ float gelu_tanh(float y) {
    float y2 = y * y;
    float z = y * fmaf(0.0356774081f, y2, 0.7978845608f);
    return y / (1.0f + __expf(-2.0f * z));
}

__global__ void quant_x_kernel(const float* __restrict__ x, signed char* __restrict__ Aq,
                               const float* __restrict__ a_scale, const float* __restrict__ a_zero,
                               long long n) {
    long long i = ((long long)blockIdx.x * blockDim.x + threadIdx.x) * 8;
    if (i >= n) return;
    float s = a_scale[0];
    float zp = rintf(a_zero[0]);
    float4 v0 = *(const float4*)(x + i);
    float4 v1 = *(const float4*)(x + i + 4);
    int q0 = (int)fakeq_int(v0.x, s, zp), q1 = (int)fakeq_int(v0.y, s, zp);
    int q2 = (int)fakeq_int(v0.z, s, zp), q3 = (int)fakeq_int(v0.w, s, zp);
    int q4 = (int)fakeq_int(v1.x, s, zp), q5 = (int)fakeq_int(v1.y, s, zp);
    int q6 = (int)fakeq_int(v1.z, s, zp), q7 = (int)fakeq_int(v1.w, s, zp);
    int lo = (q0 & 255) | ((q1 & 255) << 8) | ((q2 & 255) << 16) | ((q3 & 255) << 24);
    int hi = (q4 & 255) | ((q5 & 255) << 8) | ((q6 & 255) << 16) | ((q7 & 255) << 24);
    *(int2*)(Aq + i) = make_int2(lo, hi);
}

__global__ void quant_w_kernel(const float* __restrict__ w, signed char* __restrict__ Wq,
                               const float* __restrict__ w_scale, const float* __restrict__ w_zero,
                               long long n) {
    long long i = ((long long)blockIdx.x * blockDim.x + threadIdx.x) * 8;
    if (i >= n) return;
    long long row = i >> 10;
    float s = w_scale[row];
    float zp = rintf(w_zero[row]);
    float4 v0 = *(const float4*)(w + i);
    float4 v1 = *(const float4*)(w + i + 4);
    int q0 = (int)fakeq_int(v0.x, s, zp), q1 = (int)fakeq_int(v0.y, s, zp);
    int q2 = (int)fakeq_int(v0.z, s, zp), q3 = (int)fakeq_int(v0.w, s, zp);
    int q4 = (int)fakeq_int(v1.x, s, zp), q5 = (int)fakeq_int(v1.y, s, zp);
    int q6 = (int)fakeq_int(v1.z, s, zp), q7 = (int)fakeq_int(v1.w, s, zp);
    int lo = (q0 & 255) | ((q1 & 255) << 8) | ((q2 & 255) << 16) | ((q3 & 255) << 24);
    int hi = (q4 & 255) | ((q5 & 255) << 8) | ((q6 & 255) << 16) | ((q7 & 255) << 24);
    *(int2*)(Wq + i) = make_int2(lo, hi);
}

#define GLL(SRC, DST)                                                         \
    __builtin_amdgcn_global_load_lds(                                         \
        (const __attribute__((address_space(1))) void*)(SRC),                 \
        (__attribute__((address_space(3))) void*)(DST), 16, 0, 0)

// stage K-tile TT (A 256x64B = 2 chunks of 128 rows, B 128x64B = 1 chunk): 3 GLL/thread
#define STAGE(TT, BUF)                                            \
    do {                                                          \
        GLL(pA0 + (TT) * BK3, As + (BUF) * 16384 + dA);           \
        GLL(pA1 + (TT) * BK3, As + (BUF) * 16384 + 8192 + dA);    \
        GLL(pB0 + (TT) * BK3, Bs + (BUF) * 8192 + dA);            \
    } while (0)

__global__ __launch_bounds__(512, 4) void gemm_gelu_kernel(
    const signed char* __restrict__ Aq,   // [M][K] int8 codes
    const signed char* __restrict__ Wq,   // [I][K]
    const float* __restrict__ bias,
    const float* __restrict__ w_scale,
    const float* __restrict__ a_scale,
    float* __restrict__ out,              // [M][I] fp32
    int M, int Mtiles, int Ntiles) {
    __shared__ alignas(16) signed char As[3 * 256 * BK3];  // 48 KB
    __shared__ alignas(16) signed char Bs[3 * 128 * BK3];  // 24 KB

    // bijective XCD-aware swizzle (nwg % 8 == 0)
    int nwg = gridDim.x, bid = blockIdx.x;
    int xcd = bid & 7, lin = bid >> 3;
    int q8 = nwg >> 3, r8 = nwg & 7;
    int swz = (xcd < r8 ? xcd * (q8 + 1) : r8 * (q8 + 1) + (xcd - r8) * q8) + lin;

    // supertile order (r13): bands of 4 mt, nt-major, mt inner
    int band = swz >> 7;                 // / (4 * Ntiles), Ntiles == 32
    int r = swz & 127;
    int rem = Mtiles - band * 4;
    if (rem > 4) rem = 4;
    unsigned nt = (unsigned)r / (unsigned)rem;
    int mt = band * 4 + (r - (int)nt * rem);

    int tid = threadIdx.x;
    int wave = tid >> 6, lane = tid & 63;
    int wr = wave >> 1, wc = wave & 1;  // 4(M) x 2(N) waves, per-wave 64x64

    long long mrow0 = (long long)mt * 256;
    int ncol0 = (int)nt * 128;

    // staging: thread t covers row (chunk*128 + t>>2), LDS slot j = t&3 (16B slots).
    // rotation swizzle (HW-verified r6: 0 conflicts): LDS[row][j] = src slot (j-(row>>1))&3
    int r0 = tid >> 2;                                  // 0..127
    int slotsrc = ((tid & 3) - ((tid >> 3) & 3)) & 3;
    long long mmax = (long long)M - 1;
    long long raA0 = mrow0 + r0;         if (raA0 > mmax) raA0 = mmax;
    long long raA1 = mrow0 + 128 + r0;   if (raA1 > mmax) raA1 = mmax;
    const signed char* pA0 = Aq + raA0 * K_DIM + slotsrc * 16;
    const signed char* pA1 = Aq + raA1 * K_DIM + slotsrc * 16;
    const signed char* pB0 = Wq + ((long long)ncol0 + r0) * K_DIM + slotsrc * 16;
    int dA = tid * 16;  // linear byte dest within each 8KB chunk region

    // ds_read: lane (r = lane&15, q = lane>>4) reads slot (q + (r>>1)) & 3
    int koffb = (((lane >> 4) + ((lane >> 1) & 3)) & 3) * 16;
    int arowb = wr * 64 + (lane & 15);
    int browb = wc * 64 + (lane & 15);

    i32x4 acc[4][4];
#pragma unroll
    for (int m = 0; m < 4; ++m)
#pragma unroll
        for (int n = 0; n < 4; ++n) acc[m][n] = (i32x4)0;

    // prologue: stage tiles 0,1; wait tile 0 (tile 1's 3 stay in flight)
    STAGE(0, 0);
    STAGE(1, 1);
    asm volatile("s_waitcnt vmcnt(3)" ::: "memory");
    __builtin_amdgcn_s_barrier();

#pragma unroll
    for (int t = 0; t < NT3; ++t) {
        const int buf = t % 3;            // static under full unroll
        const int bs2 = (t + 2) % 3;
        if (t + 2 < NT3) STAGE(t + 2, bs2);  // 2-tile lead

        i32x4 a[4], b[4];
#pragma unroll
        for (int mi = 0; mi < 4; ++mi)
            a[mi] = *(const i32x4*)(As + buf * 16384 + (arowb + mi * 16) * BK3 + koffb);
#pragma unroll
        for (int n = 0; n < 4; ++n)
            b[n] = *(const i32x4*)(Bs + buf * 8192 + (browb + n * 16) * BK3 + koffb);

        __builtin_amdgcn_s_setprio(1);
#pragma unroll
        for (int mi = 0; mi < 4; ++mi)
#pragma unroll
            for (int n = 0; n < 4; ++n)
                acc[mi][n] = __builtin_amdgcn_mfma_i32_16x16x64_i8(a[mi], b[n], acc[mi][n], 0, 0, 0);
        __builtin_amdgcn_s_setprio(0);

        // ensure tile t+1 landed; keep tile t+2's 3 loads in flight
        if (t + 2 < NT3) {
            asm volatile("s_waitcnt vmcnt(3)" ::: "memory");
        } else if (t + 1 < NT3) {
            asm volatile("s_waitcnt vmcnt(0)" ::: "memory");
        }
        if (t + 1 < NT3) __builtin_amdgcn_s_barrier();
    }

    // epilogue (r13 layout): y = a_scale*w_scale[col]*(float)acc + bias[col]; tanh-GELU
    float asc = a_scale[0];
    long long row0 = mrow0 + wr * 64;
    int colb = ncol0 + wc * 64 + (lane & 15);
    int rsubE = (lane >> 4) * 4;
    bool fullTile = (mrow0 + 256 <= (long long)M);
    if (fullTile) {
#pragma unroll
        for (int n = 0; n < 4; ++n) {
            int col = colb + n * 16;
            float sc = asc * w_scale[col];
            float bz = bias[col];
#pragma unroll
            for (int m = 0; m < 4; ++m) {
                long long rb = row0 + m * 16 + rsubE;
#pragma unroll
                for (int rg = 0; rg < 4; ++rg) {
                    float y = (float)acc[m][n][rg] * sc + bz;
                    out[(rb + rg) * I_DIM + col] = gelu_tanh(y);
                }
            }
        }
    } else {
#pragma unroll
        for (int n = 0; n < 4; ++n) {
            int col = colb + n * 16;
            float sc = asc * w_scale[col];
            float bz = bias[col];
#pragma unroll
            for (int m = 0; m < 4; ++m) {
                long long rb = row0 + m * 16 + rsubE;
#pragma unroll
                for (int rg = 0; rg < 4; ++rg) {
                    long long rowi = rb + rg;
                    if (rowi < M) {
                        float y = (float)acc[m][n][rg] * sc + bz;
                        out[rowi * I_DIM + col] = gelu_tanh(y);
                    }
                }
            }
        }
    }
}

// ---- safety-net fallback (workspace too small): naive on-the-fly
__global__ void fallback_kernel(const float* __restrict__ x, const float* __restrict__ w,
                                const float* __restrict__ bias, const float* __restrict__ w_scale,
                                const float* __restrict__ w_zero, const float* __restrict__ a_scale,
                                const float* __restrict__ a_zero, float* __restrict__ out,
                                long long M) {
    long long gid = (long long)blockIdx.x * blockDim.x + threadIdx.x;
    if (gid >= M * I_DIM) return;
    int i = (int)(gid & (I_DIM - 1));
    long long row = gid >> 12;
    float as = a_scale[0], az = rintf(a_zero[0]);
    float wsc = w_scale[i], wz = rintf(w_zero[i]);
    const float* xr = x + row * K_DIM;
    const float* wrp = w + (long long)i * K_DIM;
    float accf = 0.0f;
    for (int k = 0; k < K_DIM; ++k)
        accf += fakeq_int(xr[k], as, az) * fakeq_int(wrp[k], wsc, wz);
    float y = accf * as * wsc + bias[i];
    out[gid] = 0.5f * y * (1.0f + erff(y * 0.70710678118654752f));
}

extern "C" void kernel_launch(void* const* d_in, const int* in_sizes, int n_in,
                              void* d_out, int out_size, void* d_ws, size_t ws_size,
                              hipStream_t stream) {
    const float* x       = (const float*)d_in[0];
    const float* w       = (const float*)d_in[1];
    const float* bias    = (const float*)d_in[2];
    const float* w_scale = (const float*)d_in[3];
    const float* w_zero  = (const float*)d_in[4];
    const float* a_scale = (const float*)d_in[5];
    const float* a_zero  = (const float*)d_in[6];
    float* out = (float*)d_out;

    long long n_x = in_sizes[0];  // M*K
    long long M = n_x / K_DIM;    // 12608
    size_t needA = ((size_t)n_x + 255) & ~(size_t)255;
    size_t needW = (size_t)I_DIM * K_DIM;

    if (ws_size >= needA + needW) {
        signed char* Aq = (signed char*)d_ws;
        signed char* Wq = (signed char*)((char*)d_ws + needA);

        long long blocksX = (n_x / 8 + 255) / 256;
        quant_x_kernel<<<(int)blocksX, 256, 0, stream>>>(x, Aq, a_scale, a_zero, n_x);

        long long ndw = (long long)I_DIM * K_DIM;
        long long blocksW = (ndw / 8 + 255) / 256;
        quant_w_kernel<<<(int)blocksW, 256, 0, stream>>>(w, Wq, w_scale, w_zero, ndw);

        int Mtiles = (int)((M + 255) / 256);  // 50
        int Ntiles = I_DIM / 128;             // 32
        gemm_gelu_kernel<<<Mtiles * Ntiles, 512, 0, stream>>>(Aq, Wq, bias, w_scale, a_scale,
                                                              out, (int)M, Mtiles, Ntiles);
    } else {
        long long total = M * I_DIM;
        long long blocks = (total + 255) / 256;
        fallback_kernel<<<(int)blocks, 256, 0, stream>>>(x, w, bias, w_scale, w_zero,
                                                         a_scale, a_zero, out, M);
    }
}